// Round 4
// baseline (272.053 us; speedup 1.0000x reference)
//
#include <hip/hip_runtime.h>

// change[i] (i>=1) ∝ (g(i-3) - g(i+2))^2   with g(k)=f[k] zero-padded; change[0]=0
// out[i] = (1 - change[i]/S)^5 * f[i],  S = sum(change)
// The 1/5 conv scaling cancels in change[i]/S, so we accumulate unscaled d^2.
//
// Single persistent kernel: phase1 reduce -> device-atomic grid barrier ->
// phase2 finalize. Grid 1024 blocks x 256 thr with __launch_bounds__(256,4)
// = exactly 4 blocks/CU x 256 CU co-resident, so the spin barrier is safe.

#define GRID_BLOCKS 1024
#define BLOCK 256

__device__ __forceinline__ float change_term(const float* __restrict__ f, long long i, long long n) {
    if (i < 1) return 0.0f;
    float a = (i >= 3)    ? f[i - 3] : 0.0f;
    float b = (i + 2 < n) ? f[i + 2] : 0.0f;
    float d = a - b;
    return d * d;
}

__device__ __forceinline__ float pow5(float t) {
    float t2 = t * t;
    float t4 = t2 * t2;
    return t4 * t;
}

__device__ __forceinline__ float vec_terms(float4 p, float4 c, float4 q) {
    // element j=4v+k: a=f[j-3], b=f[j+2]
    float d0 = p.y - c.z;
    float d1 = p.z - c.w;
    float d2 = p.w - q.x;
    float d3 = c.x - q.y;
    return d0 * d0 + d1 * d1 + d2 * d2 + d3 * d3;
}

__device__ __forceinline__ float4 vec_out(float4 p, float4 c, float4 q, float inv) {
    float d0 = p.y - c.z;
    float d1 = p.z - c.w;
    float d2 = p.w - q.x;
    float d3 = c.x - q.y;
    float4 o;
    o.x = pow5(1.0f - d0 * d0 * inv) * c.x;
    o.y = pow5(1.0f - d1 * d1 * inv) * c.y;
    o.z = pow5(1.0f - d2 * d2 * inv) * c.z;
    o.w = pow5(1.0f - d3 * d3 * inv) * c.w;
    return o;
}

__global__ __launch_bounds__(BLOCK, 4)
void fused_kernel(const float* __restrict__ f, int nvec, long long n,
                  float* __restrict__ sum_ws, int* __restrict__ cnt_ws,
                  float* __restrict__ out) {
    const float4* __restrict__ fv = (const float4*)f;
    float4* __restrict__ ov = (float4*)out;
    const int T = GRID_BLOCKS * BLOCK;
    const int tid = blockIdx.x * BLOCK + threadIdx.x;
    const int M = nvec - 2;  // interior vectors: v = 1 + idx, idx in [0, M)

    // ---------------- phase 1: reduce ----------------
    float acc = 0.0f;
    int idx = tid;
    for (; idx + 3 * T < M; idx += 4 * T) {
        float4 p[4], c[4], q[4];
        #pragma unroll
        for (int u = 0; u < 4; ++u) {
            int v = 1 + idx + u * T;
            p[u] = fv[v - 1];
            c[u] = fv[v];
            q[u] = fv[v + 1];
        }
        #pragma unroll
        for (int u = 0; u < 4; ++u)
            acc += vec_terms(p[u], c[u], q[u]);
    }
    for (; idx < M; idx += T) {
        int v = 1 + idx;
        acc += vec_terms(fv[v - 1], fv[v], fv[v + 1]);
    }
    if (tid == 0) {
        #pragma unroll
        for (int k = 0; k < 4; ++k) acc += change_term(f, k, n);
        long long j0 = n - 4;
        #pragma unroll
        for (int k = 0; k < 4; ++k) acc += change_term(f, j0 + k, n);
    }

    // wave (64-lane) reduction
    #pragma unroll
    for (int off = 32; off > 0; off >>= 1)
        acc += __shfl_down(acc, off, 64);
    __shared__ float smem[4];
    __shared__ float s_total;
    int lane = threadIdx.x & 63;
    int wave = threadIdx.x >> 6;
    if (lane == 0) smem[wave] = acc;
    __syncthreads();

    // ---------------- grid barrier ----------------
    if (threadIdx.x == 0) {
        float s = smem[0] + smem[1] + smem[2] + smem[3];
        atomicAdd(sum_ws, s);           // device-scope
        __threadfence();                // sum visible before arrival
        atomicAdd(cnt_ws, 1);
        while (atomicAdd(cnt_ws, 0) < GRID_BLOCKS) {
            __builtin_amdgcn_s_sleep(2);
        }
        s_total = atomicAdd(sum_ws, 0.0f);  // coherent read of final sum
    }
    __syncthreads();
    float inv = 1.0f / s_total;

    // ---------------- phase 2: finalize ----------------
    idx = tid;
    for (; idx + 3 * T < M; idx += 4 * T) {
        float4 p[4], c[4], q[4];
        #pragma unroll
        for (int u = 0; u < 4; ++u) {
            int v = 1 + idx + u * T;
            p[u] = fv[v - 1];
            c[u] = fv[v];
            q[u] = fv[v + 1];
        }
        #pragma unroll
        for (int u = 0; u < 4; ++u)
            ov[1 + idx + u * T] = vec_out(p[u], c[u], q[u], inv);
    }
    for (; idx < M; idx += T) {
        int v = 1 + idx;
        ov[v] = vec_out(fv[v - 1], fv[v], fv[v + 1], inv);
    }
    if (tid == 0) {
        // edge vectors v=0 and v=nvec-1, scalar
        #pragma unroll
        for (int k = 0; k < 4; ++k) {
            float cge = change_term(f, k, n) * inv;
            out[k] = pow5(1.0f - cge) * f[k];
        }
        long long j0 = n - 4;
        #pragma unroll
        for (int k = 0; k < 4; ++k) {
            long long j = j0 + k;
            float cge = change_term(f, j, n) * inv;
            out[j] = pow5(1.0f - cge) * f[j];
        }
    }
}

extern "C" void kernel_launch(void* const* d_in, const int* in_sizes, int n_in,
                              void* d_out, int out_size, void* d_ws, size_t ws_size,
                              hipStream_t stream) {
    const float* f = (const float*)d_in[0];
    float* out = (float*)d_out;
    float* sum_ws = (float*)d_ws;
    int* cnt_ws = (int*)((char*)d_ws + sizeof(float));
    long long n = (long long)in_sizes[0];
    int nvec = (int)(n / 4);  // n = 2^24, divisible by 4

    hipMemsetAsync(d_ws, 0, 2 * sizeof(float), stream);

    fused_kernel<<<GRID_BLOCKS, BLOCK, 0, stream>>>(f, nvec, n, sum_ws, cnt_ws, out);
}

// Round 5
// 169.199 us; speedup vs baseline: 1.6079x; 1.6079x over previous
//
#include <hip/hip_runtime.h>

// change[i] (i>=1) ∝ (g(i-3) - g(i+2))^2   with g(k)=f[k] zero-padded; change[0]=0
// out[i] = (1 - change[i]/S)^5 * f[i],  S = sum(change)
// The 1/5 conv scaling cancels in change[i]/S, so we accumulate unscaled d^2.
//
// Two one-shot kernels. Each thread handles 4 CONSECUTIVE float4 vectors
// (16 elements) via 6 float4 loads (4 center + 2 halo) -> register reuse
// halves load instructions vs the 3-loads-per-vector layout.
// R4 lesson: no grid barrier — atomic-RMW spin serialized 1024 blocks and
// cost ~150us. Two launches + L3-absorbed re-read is the right structure.

#define BLOCK 256

__device__ __forceinline__ float change_term(const float* __restrict__ f, long long i, long long n) {
    if (i < 1) return 0.0f;
    float a = (i >= 3)    ? f[i - 3] : 0.0f;
    float b = (i + 2 < n) ? f[i + 2] : 0.0f;
    float d = a - b;
    return d * d;
}

__device__ __forceinline__ float pow5(float t) {
    float t2 = t * t;
    float t4 = t2 * t2;
    return t4 * t;
}

// terms for vector v given p=fv[v-1], c=fv[v], q=fv[v+1]; element j=4v+k uses
// a=f[j-3], b=f[j+2]
__device__ __forceinline__ float vec_terms(float4 p, float4 c, float4 q) {
    float d0 = p.y - c.z;
    float d1 = p.z - c.w;
    float d2 = p.w - q.x;
    float d3 = c.x - q.y;
    return d0 * d0 + d1 * d1 + d2 * d2 + d3 * d3;
}

__device__ __forceinline__ float4 vec_out(float4 p, float4 c, float4 q, float inv) {
    float d0 = p.y - c.z;
    float d1 = p.z - c.w;
    float d2 = p.w - q.x;
    float d3 = c.x - q.y;
    float4 o;
    o.x = pow5(1.0f - d0 * d0 * inv) * c.x;
    o.y = pow5(1.0f - d1 * d1 * inv) * c.y;
    o.z = pow5(1.0f - d2 * d2 * inv) * c.z;
    o.w = pow5(1.0f - d3 * d3 * inv) * c.w;
    return o;
}

// G = (nvec-2)/4 full groups of 4 interior vectors. Group g covers vectors
// v = 1+4g .. 4+4g, i.e. elements [4+16g, 20+16g). Thread g==G (scalar) covers
// elements [0,4) and [4+16G, n).

__global__ __launch_bounds__(BLOCK)
void reduce_change_kernel(const float* __restrict__ f, int nvec, long long n,
                          float* __restrict__ sum_out) {
    const float4* __restrict__ fv = (const float4*)f;
    const int G = (nvec - 2) >> 2;
    int g = blockIdx.x * BLOCK + threadIdx.x;
    float acc = 0.0f;
    if (g < G) {
        int v = 1 + (g << 2);
        float4 r0 = fv[v - 1], r1 = fv[v],     r2 = fv[v + 1],
               r3 = fv[v + 2], r4 = fv[v + 3], r5 = fv[v + 4];
        acc = vec_terms(r0, r1, r2) + vec_terms(r1, r2, r3)
            + vec_terms(r2, r3, r4) + vec_terms(r3, r4, r5);
    } else if (g == G) {
        for (long long j = 0; j < 4; ++j) acc += change_term(f, j, n);
        for (long long j = 4LL + 16LL * G; j < n; ++j) acc += change_term(f, j, n);
    }
    // wave (64-lane) reduction
    #pragma unroll
    for (int off = 32; off > 0; off >>= 1)
        acc += __shfl_down(acc, off, 64);
    __shared__ float smem[4];
    int lane = threadIdx.x & 63;
    int wave = threadIdx.x >> 6;
    if (lane == 0) smem[wave] = acc;
    __syncthreads();
    if (threadIdx.x == 0) {
        float s = smem[0] + smem[1] + smem[2] + smem[3];
        atomicAdd(sum_out, s);
    }
}

__global__ __launch_bounds__(BLOCK)
void finalize_kernel(const float* __restrict__ f, int nvec, long long n,
                     const float* __restrict__ sum_in,
                     float* __restrict__ out) {
    const float4* __restrict__ fv = (const float4*)f;
    float4* __restrict__ ov = (float4*)out;
    const int G = (nvec - 2) >> 2;
    int g = blockIdx.x * BLOCK + threadIdx.x;
    if (g < G) {
        int v = 1 + (g << 2);
        float4 r0 = fv[v - 1], r1 = fv[v],     r2 = fv[v + 1],
               r3 = fv[v + 2], r4 = fv[v + 3], r5 = fv[v + 4];
        float inv = 1.0f / *sum_in;
        ov[v]     = vec_out(r0, r1, r2, inv);
        ov[v + 1] = vec_out(r1, r2, r3, inv);
        ov[v + 2] = vec_out(r2, r3, r4, inv);
        ov[v + 3] = vec_out(r3, r4, r5, inv);
    } else if (g == G) {
        float inv = 1.0f / *sum_in;
        for (long long j = 0; j < 4; ++j) {
            float c = change_term(f, j, n) * inv;
            out[j] = pow5(1.0f - c) * f[j];
        }
        for (long long j = 4LL + 16LL * G; j < n; ++j) {
            float c = change_term(f, j, n) * inv;
            out[j] = pow5(1.0f - c) * f[j];
        }
    }
}

extern "C" void kernel_launch(void* const* d_in, const int* in_sizes, int n_in,
                              void* d_out, int out_size, void* d_ws, size_t ws_size,
                              hipStream_t stream) {
    const float* f = (const float*)d_in[0];
    float* out = (float*)d_out;
    float* sum_ws = (float*)d_ws;
    long long n = (long long)in_sizes[0];
    int nvec = (int)(n / 4);  // n = 2^24, divisible by 4

    hipMemsetAsync(d_ws, 0, sizeof(float), stream);

    int G = (nvec - 2) >> 2;
    int grid = (G + 1 + BLOCK - 1) / BLOCK;
    reduce_change_kernel<<<grid, BLOCK, 0, stream>>>(f, nvec, n, sum_ws);
    finalize_kernel<<<grid, BLOCK, 0, stream>>>(f, nvec, n, sum_ws, out);
}

// Round 7
// 119.124 us; speedup vs baseline: 2.2838x; 1.4204x over previous
//
#include <hip/hip_runtime.h>

// change[i] (i>=1) ∝ (g(i-3) - g(i+2))^2   with g(k)=f[k] zero-padded; change[0]=0
// out[i] = (1 - change[i]/S)^5 * f[i],  S = sum(change)
// The 1/5 conv scaling cancels in change[i]/S, so we accumulate unscaled d^2.
//
// Structure = R3 (best measured: 128 us total), plus:
//  - 16 bucketed partial sums on separate cache lines (atomic serialization
//    at ONE address was the R2/R4/R5 regression: ~5 ns per same-line RMW,
//    monotone in block count). 2048 blocks / 16 lines -> ~0.6 us, hidden.
//  - nontemporal stores for out (write-once data), via native vector type
//    (clang builtin rejects HIP_vector_type float4).

#define BLOCK 256
#define RGRID 2048
#define NBUCKET 16
#define BUCKET_STRIDE 64   // floats; 256 B between buckets -> distinct lines

typedef __attribute__((ext_vector_type(4))) float vfloat4;

__device__ __forceinline__ float change_term(const float* __restrict__ f, long long i, long long n) {
    if (i < 1) return 0.0f;
    float a = (i >= 3)    ? f[i - 3] : 0.0f;
    float b = (i + 2 < n) ? f[i + 2] : 0.0f;
    float d = a - b;
    return d * d;
}

__device__ __forceinline__ float pow5(float t) {
    float t2 = t * t;
    float t4 = t2 * t2;
    return t4 * t;
}

// terms for vector v given p=fv[v-1], c=fv[v], q=fv[v+1]; element j=4v+k uses
// a=f[j-3], b=f[j+2]
__device__ __forceinline__ float vec_terms(float4 p, float4 c, float4 q) {
    float d0 = p.y - c.z;
    float d1 = p.z - c.w;
    float d2 = p.w - q.x;
    float d3 = c.x - q.y;
    return d0 * d0 + d1 * d1 + d2 * d2 + d3 * d3;
}

__device__ __forceinline__ vfloat4 vec_out(float4 p, float4 c, float4 q, float inv) {
    float d0 = p.y - c.z;
    float d1 = p.z - c.w;
    float d2 = p.w - q.x;
    float d3 = c.x - q.y;
    vfloat4 o;
    o.x = pow5(1.0f - d0 * d0 * inv) * c.x;
    o.y = pow5(1.0f - d1 * d1 * inv) * c.y;
    o.z = pow5(1.0f - d2 * d2 * inv) * c.z;
    o.w = pow5(1.0f - d3 * d3 * inv) * c.w;
    return o;
}

__global__ __launch_bounds__(BLOCK)
void reduce_change_kernel(const float* __restrict__ f, int nvec, long long n,
                          float* __restrict__ sum_out) {
    const float4* __restrict__ fv = (const float4*)f;
    const int T = RGRID * BLOCK;
    const int tid = blockIdx.x * BLOCK + threadIdx.x;
    const int M = nvec - 2;  // interior vectors: v = 1 + idx, idx in [0, M)
    float acc = 0.0f;

    int idx = tid;
    // unrolled-by-4: 12 independent, perfectly-coalesced float4 loads in flight
    for (; idx + 3 * T < M; idx += 4 * T) {
        float4 p[4], c[4], q[4];
        #pragma unroll
        for (int u = 0; u < 4; ++u) {
            int v = 1 + idx + u * T;
            p[u] = fv[v - 1];
            c[u] = fv[v];
            q[u] = fv[v + 1];
        }
        #pragma unroll
        for (int u = 0; u < 4; ++u)
            acc += vec_terms(p[u], c[u], q[u]);
    }
    for (; idx < M; idx += T) {
        int v = 1 + idx;
        acc += vec_terms(fv[v - 1], fv[v], fv[v + 1]);
    }
    if (tid == 0) {
        #pragma unroll
        for (int k = 0; k < 4; ++k) acc += change_term(f, k, n);
        long long j0 = n - 4;
        #pragma unroll
        for (int k = 0; k < 4; ++k) acc += change_term(f, j0 + k, n);
    }

    // wave (64-lane) reduction
    #pragma unroll
    for (int off = 32; off > 0; off >>= 1)
        acc += __shfl_down(acc, off, 64);
    __shared__ float smem[4];
    int lane = threadIdx.x & 63;
    int wave = threadIdx.x >> 6;
    if (lane == 0) smem[wave] = acc;
    __syncthreads();
    if (threadIdx.x == 0) {
        float s = smem[0] + smem[1] + smem[2] + smem[3];
        atomicAdd(&sum_out[(blockIdx.x & (NBUCKET - 1)) * BUCKET_STRIDE], s);
    }
}

__device__ __forceinline__ float bucket_sum(const float* __restrict__ sum_in) {
    float s = 0.0f;
    #pragma unroll
    for (int b = 0; b < NBUCKET; ++b) s += sum_in[b * BUCKET_STRIDE];
    return s;
}

__global__ __launch_bounds__(BLOCK)
void finalize_kernel(const float* __restrict__ f, int nvec, long long n,
                     const float* __restrict__ sum_in,
                     float* __restrict__ out) {
    const float4* __restrict__ fv = (const float4*)f;
    vfloat4* __restrict__ ov = (vfloat4*)out;
    const int M = nvec - 2;       // interior vectors
    const int T = (M + 1) >> 1;   // each thread handles 2 strided interior vectors
    int tid = blockIdx.x * BLOCK + threadIdx.x;
    if (tid < T) {
        int v1 = 1 + tid;
        bool has2 = (tid + T) < M;
        int v2 = has2 ? (1 + tid + T) : v1;
        // issue all 6 loads before compute
        float4 p1 = fv[v1 - 1], c1 = fv[v1], q1 = fv[v1 + 1];
        float4 p2 = fv[v2 - 1], c2 = fv[v2], q2 = fv[v2 + 1];
        float inv = 1.0f / bucket_sum(sum_in);
        __builtin_nontemporal_store(vec_out(p1, c1, q1, inv), &ov[v1]);
        if (has2) __builtin_nontemporal_store(vec_out(p2, c2, q2, inv), &ov[v2]);
    }
    if (tid == 0) {
        // edge vectors v=0 and v=nvec-1, scalar
        float inv = 1.0f / bucket_sum(sum_in);
        #pragma unroll
        for (int k = 0; k < 4; ++k) {
            float cge = change_term(f, k, n) * inv;
            out[k] = pow5(1.0f - cge) * f[k];
        }
        long long j0 = n - 4;
        #pragma unroll
        for (int k = 0; k < 4; ++k) {
            long long j = j0 + k;
            float cge = change_term(f, j, n) * inv;
            out[j] = pow5(1.0f - cge) * f[j];
        }
    }
}

extern "C" void kernel_launch(void* const* d_in, const int* in_sizes, int n_in,
                              void* d_out, int out_size, void* d_ws, size_t ws_size,
                              hipStream_t stream) {
    const float* f = (const float*)d_in[0];
    float* out = (float*)d_out;
    float* sum_ws = (float*)d_ws;
    long long n = (long long)in_sizes[0];
    int nvec = (int)(n / 4);  // n = 2^24, divisible by 4

    (void)hipMemsetAsync(d_ws, 0, NBUCKET * BUCKET_STRIDE * sizeof(float), stream);

    reduce_change_kernel<<<RGRID, BLOCK, 0, stream>>>(f, nvec, n, sum_ws);

    int M = nvec - 2;
    int T = (M + 1) >> 1;
    int fgrid = (T + BLOCK - 1) / BLOCK;
    finalize_kernel<<<fgrid, BLOCK, 0, stream>>>(f, nvec, n, sum_ws, out);
}